// Round 12
// baseline (276.791 us; speedup 1.0000x reference)
//
#include <hip/hip_runtime.h>
#include <hip/hip_bf16.h>
#include <math.h>
#include <type_traits>

// ---------------------------------------------------------------------------
// SelfAttention B=4,T=2048,D=1024 fp32 in/out.
// Round 22: revert to R16 core (best measured) + SPLIT-K div.
//   R13-R21: five schedule families all land 64-77us/dispatch -> structure-
//   insensitive. The one exploitable asymmetry: per-CU throughput scales
//   with co-resident blocks (proj@3/CU does 1.5x the FLOP rate of exp@2 and
//   div@1 in identical wall time). div = 256 blocks = 1/CU is the worst.
//   Fix: split div's K=2048 into 2 halves over z (grid z=8: batch=z>>1,
//   khalf=z&1); each block atomicAdds partial/rowsum into out (division is
//   linear). div geometry becomes exp's (512 blocks = 2/CU, 32 K-tiles).
//   out zeroed in prep (+512 blocks, ~5us). Atomics conflict-free (2
//   touches/address). Discriminator: div ~40-48us => concurrency model
//   confirmed; div ~65us => unexplained per-dispatch floor -> declare.
// Core (R16, verified): 256x128 block, 8 waves of 64x64 (acc[2][2]), BK=32,
// 3-ring 72KB LDS, STAGE(kt+2) after top barrier, counted vmcnt(3)
// (vmcnt(0) last tile only). Stripe layout (0-conflict, 1KB-contig
// staging): unit u=(r>>5)*(K>>4)+(k>>4), el p=((r&31)+32*((k>>3)&1))*8+(k&7).
// prep: LDS-transpose cast (64KB contiguous writes) + rowsum & out zeroing.
// Epilogues verified; absmax may move +-1-2 fp32 ulp from split-K reorder.
// ---------------------------------------------------------------------------

typedef short shortx8 __attribute__((ext_vector_type(8)));
typedef short shortx4 __attribute__((ext_vector_type(4)));
typedef float floatx16 __attribute__((ext_vector_type(16)));
typedef __attribute__((address_space(3))) void lds_void_t;
typedef __attribute__((address_space(1))) const void gmem_void_t;

#define GLD16(gp, lp) \
    __builtin_amdgcn_global_load_lds((gmem_void_t*)(gp), (lds_void_t*)(lp), 16, 0, 0)

#define MODE_PROJ 0   // z=0,1: C=bf16(A B^T) striped;  z=2: Vt striped
#define MODE_EXP  1   // C = bf16(exp(alpha A B^T)) striped, rowsum += exp
#define MODE_DIV  2   // C += fp32(A B^T)/rowsum[row] (split-K atomics)

// C[M,N] = f(A[M,K] @ B[N,K]^T). A,B striped (k-dim = K). z-batched.
// 256x128 tile, BK=32, 8 waves: wm=(w>>1)*64, wn=(w&1)*64, acc[2][2].
// LDS buffer: A units (rg 0..7, hp 0..1) at (rg*2+hp)*512; B units
// (rg 0..3, hp 0..1) at 8192+(rg*2+hp)*512. 12288 els = 24KB; x3 ring = 72KB.
template <int MODE>
__global__ __launch_bounds__(512, 4) void mfma_gemm_abt(
    const __hip_bfloat16* __restrict__ A, const __hip_bfloat16* __restrict__ B,
    void* __restrict__ Cv, float* __restrict__ rowsum,
    __hip_bfloat16* __restrict__ Vt,
    int M, int N, int K, long sA, long sB, long sC, float alpha)
{
    __shared__ __hip_bfloat16 lds[3 * 12288];   // 72KB -> 2 blocks/CU

    using CT = std::conditional_t<MODE == MODE_DIV, float, __hip_bfloat16>;

    const int z  = blockIdx.z;
    const int zb = (MODE == MODE_DIV) ? (z >> 1) : z;   // batch index
    A += (long)zb * sA;
    B += (long)zb * sB;
    CT* C = (CT*)Cv + (long)zb * sC;

    // K-tile range: div splits K over z&1; others run the full range.
    const int ktS = (MODE == MODE_DIV) ? (z & 1) * (K >> 6) : 0;
    const int ktE = ktS + ((MODE == MODE_DIV) ? (K >> 6) : (K >> 5));

    const int t     = threadIdx.x;          // 0..511
    const int wave  = t >> 6;               // 0..7
    const int lane  = t & 63;
    const int m0    = blockIdx.x * 256;
    const int n0    = blockIdx.y * 128;
    const int wm    = (wave >> 1) * 64;     // 0,64,128,192
    const int wn    = (wave & 1) * 64;      // 0,64
    const int lrow  = lane & 31;            // col of C
    const int lhalf = lane >> 5;            // +4 rows in C

    // --- staging: wave w owns A units (rg = m0/32 + w, kg = 2kt+q, q=0,1)
    //     and B unit (rg = n0/32 + (w>>1), kg = 2kt + (w&1)).
    const long KU   = (long)(K >> 4);       // k-units per row-group
    const long aOff = (long)((m0 >> 5) + wave) * KU * 512 + lane * 8;
    const long bOff = ((long)((n0 >> 5) + (wave >> 1)) * KU + (wave & 1)) * 512
                      + lane * 8;
    const int  dA   = wave * 1024;          // LDS slot (w*2+q)*512, q folds in
    const int  dB   = 8192 + wave * 512;    // = 8192 + ((w>>1)*2+(w&1))*512

    // --- fragment reads: A unit (rb=(w>>1)*2+i, hp=s) at slot (rb*2+hp)*512;
    //     lane-linear chunk l*8 (R13-verified conflict-free).
    const int raB = (wave >> 1) * 2048 + lane * 8;       // + (2i+s)*512
    const int rbB = 8192 + (wave & 1) * 2048 + lane * 8; // + (2j+s)*512

#define STAGE(bo_, k2_) do {                                               \
        GLD16(A + aOff + (long)(k2_) * 512,       lds + (bo_) + dA);       \
        GLD16(A + aOff + (long)((k2_) + 1) * 512, lds + (bo_) + dA + 512); \
        GLD16(B + bOff + (long)(k2_) * 512,       lds + (bo_) + dB);       \
    } while (0)

    floatx16 acc[2][2] = {};

    STAGE(0, 2 * ktS);                      // tile ktS   -> ring 0
    STAGE(12288, 2 * ktS + 2);              // tile ktS+1 -> ring 1

    int rCur = 0;                           // ring offset of tile kt (els)
    int rNxt = 24576;                       // ring offset of tile kt+2

    for (int kt = ktS; kt < ktE; ++kt) {
        // wait: tile kt's 3 loads done; tile kt+1's 3 stay in flight (T4)
        if (kt == ktE - 1) {
            asm volatile("s_waitcnt vmcnt(0)" ::: "memory");
        } else {
            asm volatile("s_waitcnt vmcnt(3)" ::: "memory");
        }
        __builtin_amdgcn_s_barrier();
        // ring[rNxt]'s last readers were iter kt-1; all retired before this
        // barrier -> safe to overwrite now.
        if (kt + 2 < ktE)
            STAGE(rNxt, 2 * (kt + 2));

        const __hip_bfloat16* Ls = lds + rCur;

        #pragma unroll
        for (int s = 0; s < 2; ++s) {             // two K=16 steps
            shortx8 a[2], b[2];
            #pragma unroll
            for (int i = 0; i < 2; ++i)
                a[i] = *(const shortx8*)(Ls + raB + (2 * i + s) * 512);
            #pragma unroll
            for (int j = 0; j < 2; ++j)
                b[j] = *(const shortx8*)(Ls + rbB + (2 * j + s) * 512);
            __builtin_amdgcn_s_setprio(1);
            #pragma unroll
            for (int i = 0; i < 2; ++i)
                #pragma unroll
                for (int j = 0; j < 2; ++j)
                    acc[i][j] = __builtin_amdgcn_mfma_f32_32x32x16_bf16(
                        a[i], b[j], acc[i][j], 0, 0, 0);
            __builtin_amdgcn_s_setprio(0);
        }
        rCur = (rCur == 24576) ? 0 : rCur + 12288;
        rNxt = (rNxt == 24576) ? 0 : rNxt + 12288;
    }
#undef STAGE

    // stripe store index for C striped with k-dim = N
    auto sidx = [&](int row, int col) -> long {
        return ((long)(row >> 5) * (N >> 4) + (col >> 4)) * 512
             + ((row & 31) + 32 * ((col >> 3) & 1)) * 8 + (col & 7);
    };

    // C/D layout (verified m74/m101): col = lane&31,
    // row = (reg&3) + 8*(reg>>2) + 4*(lane>>5),  reg in [0,16)
    if constexpr (MODE == MODE_PROJ) {
        if (z == 2) {
            // V -> Vt striped over (rows=d 1024, k=t 2048): per-slice TD els
            const int bz   = m0 >> 11;          // batch = row / T, T=2048
            const long bo  = (long)bz * N * 2048;
            #pragma unroll
            for (int i = 0; i < 2; ++i)
                #pragma unroll
                for (int j = 0; j < 2; ++j)
                    #pragma unroll
                    for (int g = 0; g < 4; ++g) {
                        const int t0 = (m0 + wm + 32 * i + g * 8 + 4 * lhalf) & 2047;
                        const int d  = n0 + wn + 32 * j + lrow;
                        shortx4 pk;
                        #pragma unroll
                        for (int r = 0; r < 4; ++r) {
                            __hip_bfloat16 hb = __float2bfloat16(acc[i][j][4 * g + r]);
                            pk[r] = *(short*)&hb;
                        }
                        const long idx = bo
                            + ((long)(d >> 5) * 128 + (t0 >> 4)) * 512
                            + ((d & 31) + 32 * ((t0 >> 3) & 1)) * 8 + (t0 & 7);
                        *(shortx4*)(Vt + idx) = pk;   // 4 consecutive t els
                    }
        } else {
            #pragma unroll
            for (int i = 0; i < 2; ++i)
                #pragma unroll
                for (int j = 0; j < 2; ++j)
                    #pragma unroll
                    for (int g = 0; g < 4; ++g)
                        #pragma unroll
                        for (int r = 0; r < 4; ++r) {
                            const int row = m0 + wm + 32 * i + g * 8 + 4 * lhalf + r;
                            const int col = n0 + wn + 32 * j + lrow;
                            C[sidx(row, col)] = __float2bfloat16(acc[i][j][4 * g + r]);
                        }
        }
    } else if constexpr (MODE == MODE_EXP) {
        #pragma unroll
        for (int i = 0; i < 2; ++i) {
            float rs[16];
            #pragma unroll
            for (int reg = 0; reg < 16; ++reg) rs[reg] = 0.0f;
            #pragma unroll
            for (int j = 0; j < 2; ++j)
                #pragma unroll
                for (int g = 0; g < 4; ++g)
                    #pragma unroll
                    for (int r = 0; r < 4; ++r) {
                        const int row = m0 + wm + 32 * i + g * 8 + 4 * lhalf + r;
                        const int col = n0 + wn + 32 * j + lrow;
                        const float e = __expf(acc[i][j][4 * g + r] * alpha);
                        rs[4 * g + r] += e;
                        C[sidx(row, col)] = __float2bfloat16(e);
                    }
            #pragma unroll
            for (int reg = 0; reg < 16; ++reg) {
                float v = rs[reg];
                v += __shfl_xor(v, 1);
                v += __shfl_xor(v, 2);
                v += __shfl_xor(v, 4);
                v += __shfl_xor(v, 8);
                v += __shfl_xor(v, 16);
                if (lrow == 0) {
                    const long row = m0 + wm + 32 * i + (reg >> 2) * 8 + 4 * lhalf + (reg & 3);
                    atomicAdd(&rowsum[(long)zb * M + row], v);
                }
            }
        }
    } else {  // MODE_DIV: out row-major fp32, split-K partial via atomics
        #pragma unroll
        for (int i = 0; i < 2; ++i) {
            float inv[16];
            #pragma unroll
            for (int g = 0; g < 4; ++g)
                #pragma unroll
                for (int r = 0; r < 4; ++r) {
                    const long row = m0 + wm + 32 * i + g * 8 + 4 * lhalf + r;
                    inv[4 * g + r] = 1.0f / rowsum[(long)zb * M + row];
                }
            #pragma unroll
            for (int j = 0; j < 2; ++j)
                #pragma unroll
                for (int g = 0; g < 4; ++g)
                    #pragma unroll
                    for (int r = 0; r < 4; ++r) {
                        const long row = m0 + wm + 32 * i + g * 8 + 4 * lhalf + r;
                        const long col = n0 + wn + 32 * j + lrow;
                        atomicAdd(&C[row * N + col],
                                  acc[i][j][4 * g + r] * inv[4 * g + r]);
                    }
        }
    }
}

// prep: cast x / Wq|Wk|Wv fp32->bf16 into stripe layout via LDS transpose.
// Block = one 32-row group x K=1024: coalesced float4 reads -> striped LDS
// image (64KB) -> 64KB CONTIGUOUS global write. Blocks 0..255: xb;
// 256..351: Wb. Blocks 0..31 also zero rowsum. Blocks 352..863 zero out
// (64KB each; required by div's split-K atomicAdd).
__global__ __launch_bounds__(256) void prep(
    const float* __restrict__ x,
    const float* __restrict__ W0, const float* __restrict__ W1,
    const float* __restrict__ W2,
    __hip_bfloat16* __restrict__ xb, __hip_bfloat16* __restrict__ Wb,
    float* __restrict__ rowsum, float* __restrict__ outz)
{
    __shared__ __hip_bfloat16 sb[32768];    // 64KB striped image

    const int b  = blockIdx.x;
    const int tt = threadIdx.x;             // 0..255

    if (b >= 352) {                         // zero out: 512 blocks x 64KB
        float4 zz; zz.x = zz.y = zz.z = zz.w = 0.0f;
        float4* o = (float4*)outz + (long)(b - 352) * 4096;
        #pragma unroll
        for (int it = 0; it < 16; ++it)
            o[it * 256 + tt] = zz;
        return;
    }

    if (b < 32) {
        float4 zz; zz.x = zz.y = zz.z = zz.w = 0.0f;
        ((float4*)rowsum)[b * 256 + tt] = zz;
    }

    const float* src;
    __hip_bfloat16* dst;
    if (b < 256) {
        src = x + (long)b * 32 * 1024;
        dst = xb + (long)b * 32768;
    } else {
        const int w  = (b - 256) >> 5;
        const int rg = (b - 256) & 31;
        src = ((w == 0) ? W0 : (w == 1) ? W1 : W2) + (long)rg * 32 * 1024;
        dst = Wb + (long)w * 1048576 + (long)rg * 32768;
    }

    #pragma unroll
    for (int it = 0; it < 32; ++it) {
        const int idx4 = it * 256 + tt;         // float4 index in row-major
        const float4 f = ((const float4*)src)[idx4];
        const int row = idx4 >> 8;              // 256 float4 per row
        const int k0  = (idx4 & 255) << 2;
        const int p   = ((row & 31) + 32 * ((k0 >> 3) & 1)) * 8 + (k0 & 7);
        shortx4 pk;
        __hip_bfloat16 h0 = __float2bfloat16(f.x); pk[0] = *(short*)&h0;
        __hip_bfloat16 h1 = __float2bfloat16(f.y); pk[1] = *(short*)&h1;
        __hip_bfloat16 h2 = __float2bfloat16(f.z); pk[2] = *(short*)&h2;
        __hip_bfloat16 h3 = __float2bfloat16(f.w); pk[3] = *(short*)&h3;
        *(shortx4*)(sb + (k0 >> 4) * 512 + p) = pk;
    }
    __syncthreads();

    #pragma unroll
    for (int ot = 0; ot < 16; ++ot) {
        const int off = ot * 2048 + tt * 8;
        *(shortx8*)(dst + off) = *(const shortx8*)(sb + off);
    }
}

extern "C" void kernel_launch(void* const* d_in, const int* in_sizes, int n_in,
                              void* d_out, int out_size, void* d_ws, size_t ws_size,
                              hipStream_t stream)
{
    constexpr int  Bb = 4, T = 2048, D = 1024;
    constexpr int  M  = Bb * T;                 // 8192
    constexpr long TD = (long)T * D;            // 2,097,152
    constexpr long TT = (long)T * T;            // 4,194,304
    constexpr long MD = (long)M * D;            // 8,388,608

    const float* x  = (const float*)d_in[0];
    const float* Wq = (const float*)d_in[1];
    const float* Wk = (const float*)d_in[2];
    const float* Wv = (const float*)d_in[3];
    float* out = (float*)d_out;

    // workspace: Q|K|Vt (bf16 16MB each) | P (bf16 33.6MB) | xb (16MB)
    //            | Wb (6MB) | rowsum (32KB)   -> ~104 MB  (all striped)
    __hip_bfloat16* Q  = (__hip_bfloat16*)d_ws;
    __hip_bfloat16* Kb = Q + MD;
    __hip_bfloat16* Vt = Kb + MD;
    __hip_bfloat16* P  = Vt + MD;
    __hip_bfloat16* xb = P + (long)Bb * TT;
    __hip_bfloat16* Wb = xb + MD;
    float*     rowsum  = (float*)(Wb + 3L * D * D);

    prep<<<dim3(864), dim3(256), 0, stream>>>(x, Wq, Wk, Wv, xb, Wb, rowsum, out);

    dim3 blk(512);

    // projections: z=0 -> Q, z=1 -> K, z=2 -> Vt (striped)
    mfma_gemm_abt<MODE_PROJ><<<dim3(M / 256, D / 128, 3), blk, 0, stream>>>(
        xb, Wb, Q, nullptr, Vt, M, D, D, 0, (long)D * D, MD, 1.0f);

    // P = exp(Q K^T / 32) bf16 striped, rowsum via atomics
    mfma_gemm_abt<MODE_EXP><<<dim3(T / 256, T / 128, Bb), blk, 0, stream>>>(
        Q, Kb, P, rowsum, nullptr, T, T, D, TD, TD, TT, 0.03125f);

    // out += (P @ Vt^T)_half / rowsum[row]  (split-K over z&1, fp32 atomics)
    mfma_gemm_abt<MODE_DIV><<<dim3(T / 256, D / 128, 2 * Bb), blk, 0, stream>>>(
        P, Vt, out, rowsum, nullptr, T, D, T, TT, TD, TD, 1.0f);

    (void)in_sizes; (void)n_in; (void)out_size; (void)ws_size;
}

// Round 14
// 239.621 us; speedup vs baseline: 1.1551x; 1.1551x over previous
//
#include <hip/hip_runtime.h>
#include <hip/hip_bf16.h>
#include <math.h>
#include <type_traits>

// ---------------------------------------------------------------------------
// SelfAttention B=4,T=2048,D=1024 fp32 in/out.
// Round 24 = Round 23 RESUBMISSION (bench infra failed: "container failed
// twice", no kernel diagnostics; audit found no hang/OOB risk -- barriers
// uniform per block, all indices bounds-checked, resource shape == R16/R22).
//
// Round 23: DAG repacking -- fuse projV into the exp dispatch.
//   R22: split-K atomics regressed (out RMW traffic 64MB+zero 32MB) ->
//   reverted. 13-round ledger: dispatch wall ~66us is nearly WORK-
//   INSENSITIVE (proj 51.5GF@66us=783TF vs exp 34.4GF@66us=521TF), and
//   ~50us of R16's 245.6 total is prep+gaps. So repack the DAG:
//     prep -> projQK(z=0,1; 512 blk) -> [exp(512 blk) | projV(256 blk)]
//     fused as ONE 768-block dispatch -> div (R16-exact, 256 blk).
//   projV does not feed exp (exp reads only Q,K), so fusion is legal; the
//   fused dispatch carries the proj-class load (51.6GF) that demonstrably
//   runs in the same ~66us. Saves ~1/3 of proj + one dispatch boundary.
// Core (R16, verified, unchanged): 256x128 block, 8 waves 64x64 acc[2][2],
// BK=32, 3-ring 72KB LDS, STAGE(kt+2) after top barrier, counted vmcnt(3),
// vmcnt(0) last tile only. Stripe layout (0-conflict reads, 1KB-contiguous
// staging): unit u=(r>>5)*(K>>4)+(k>>4), el p=((r&31)+32*((k>>3)&1))*8+(k&7).
// Epilogues byte-identical per element -> absmax must stay 0.0004882812.
// ---------------------------------------------------------------------------

typedef short shortx8 __attribute__((ext_vector_type(8)));
typedef short shortx4 __attribute__((ext_vector_type(4)));
typedef float floatx16 __attribute__((ext_vector_type(16)));
typedef __attribute__((address_space(3))) void lds_void_t;
typedef __attribute__((address_space(1))) const void gmem_void_t;

#define GLD16(gp, lp) \
    __builtin_amdgcn_global_load_lds((gmem_void_t*)(gp), (lds_void_t*)(lp), 16, 0, 0)

#define MODE_PROJ 0   // C=bf16(A B^T) striped (VTP: Vt-transposed store)
#define MODE_EXP  1   // C = bf16(exp(alpha A B^T)) striped, rowsum += exp
#define MODE_DIV  2   // C = fp32(A B^T) / rs[row], row-major

// One 256x128 output tile of C = f(A[.,K] @ B[.,K]^T), A/B/rs batch-resolved.
// 8 waves: wm=(w>>1)*64, wn=(w&1)*64, acc[2][2]. BK=32, 3-ring in lds.
template <int MODE, bool VTP>
__device__ __forceinline__ void gemm_core(
    const __hip_bfloat16* __restrict__ A, const __hip_bfloat16* __restrict__ B,
    void* __restrict__ Cv, float* __restrict__ rs,
    __hip_bfloat16* __restrict__ Vt,
    int N, int K, float alpha, int m0, int n0, __hip_bfloat16* lds)
{
    using CT = std::conditional_t<MODE == MODE_DIV, float, __hip_bfloat16>;
    CT* C = (CT*)Cv;

    const int t     = threadIdx.x;          // 0..511
    const int wave  = t >> 6;               // 0..7
    const int lane  = t & 63;
    const int wm    = (wave >> 1) * 64;     // 0,64,128,192
    const int wn    = (wave & 1) * 64;      // 0,64
    const int lrow  = lane & 31;            // col of C
    const int lhalf = lane >> 5;            // +4 rows in C

    // staging: wave w owns A units (rg = m0/32 + w) and B unit
    // (rg = n0/32 + (w>>1), kg parity w&1).
    const long KU   = (long)(K >> 4);       // k-units per row-group
    const long aOff = (long)((m0 >> 5) + wave) * KU * 512 + lane * 8;
    const long bOff = ((long)((n0 >> 5) + (wave >> 1)) * KU + (wave & 1)) * 512
                      + lane * 8;
    const int  dA   = wave * 1024;
    const int  dB   = 8192 + wave * 512;

    // fragment reads: lane-linear chunks (R13-verified conflict-free)
    const int raB = (wave >> 1) * 2048 + lane * 8;       // + (2i+s)*512
    const int rbB = 8192 + (wave & 1) * 2048 + lane * 8; // + (2j+s)*512

#define STAGE(bo_, k2_) do {                                               \
        GLD16(A + aOff + (long)(k2_) * 512,       lds + (bo_) + dA);       \
        GLD16(A + aOff + (long)((k2_) + 1) * 512, lds + (bo_) + dA + 512); \
        GLD16(B + bOff + (long)(k2_) * 512,       lds + (bo_) + dB);       \
    } while (0)

    floatx16 acc[2][2] = {};
    const int KT = K >> 5;

    STAGE(0, 0);                            // tile 0 -> ring 0
    STAGE(12288, 2);                        // tile 1 -> ring 1
    int rCur = 0;                           // ring offset of tile kt (els)
    int rNxt = 24576;                       // ring offset of tile kt+2

    for (int kt = 0; kt < KT; ++kt) {
        if (kt == KT - 1) {
            asm volatile("s_waitcnt vmcnt(0)" ::: "memory");
        } else {
            asm volatile("s_waitcnt vmcnt(3)" ::: "memory");
        }
        __builtin_amdgcn_s_barrier();
        if (kt + 2 < KT)
            STAGE(rNxt, 2 * (kt + 2));

        const __hip_bfloat16* Ls = lds + rCur;

        #pragma unroll
        for (int s = 0; s < 2; ++s) {             // two K=16 steps
            shortx8 a[2], b[2];
            #pragma unroll
            for (int i = 0; i < 2; ++i)
                a[i] = *(const shortx8*)(Ls + raB + (2 * i + s) * 512);
            #pragma unroll
            for (int j = 0; j < 2; ++j)
                b[j] = *(const shortx8*)(Ls + rbB + (2 * j + s) * 512);
            __builtin_amdgcn_s_setprio(1);
            #pragma unroll
            for (int i = 0; i < 2; ++i)
                #pragma unroll
                for (int j = 0; j < 2; ++j)
                    acc[i][j] = __builtin_amdgcn_mfma_f32_32x32x16_bf16(
                        a[i], b[j], acc[i][j], 0, 0, 0);
            __builtin_amdgcn_s_setprio(0);
        }
        rCur = (rCur == 24576) ? 0 : rCur + 12288;
        rNxt = (rNxt == 24576) ? 0 : rNxt + 12288;
    }
#undef STAGE

    // stripe store index for C striped with k-dim = N
    auto sidx = [&](int row, int col) -> long {
        return ((long)(row >> 5) * (N >> 4) + (col >> 4)) * 512
             + ((row & 31) + 32 * ((col >> 3) & 1)) * 8 + (col & 7);
    };

    // C/D layout (verified m74/m101): col = lane&31,
    // row = (reg&3) + 8*(reg>>2) + 4*(lane>>5),  reg in [0,16)
    if constexpr (MODE == MODE_PROJ && VTP) {
        // V -> Vt striped over (rows=d 1024, k=t 2048)
        const int bz   = m0 >> 11;              // batch = global row / T
        const long bo2 = (long)bz * N * 2048;
        #pragma unroll
        for (int i = 0; i < 2; ++i)
            #pragma unroll
            for (int j = 0; j < 2; ++j)
                #pragma unroll
                for (int g = 0; g < 4; ++g) {
                    const int t0 = (m0 + wm + 32 * i + g * 8 + 4 * lhalf) & 2047;
                    const int d  = n0 + wn + 32 * j + lrow;
                    shortx4 pk;
                    #pragma unroll
                    for (int r = 0; r < 4; ++r) {
                        __hip_bfloat16 hb = __float2bfloat16(acc[i][j][4 * g + r]);
                        pk[r] = *(short*)&hb;
                    }
                    const long idx = bo2
                        + ((long)(d >> 5) * 128 + (t0 >> 4)) * 512
                        + ((d & 31) + 32 * ((t0 >> 3) & 1)) * 8 + (t0 & 7);
                    *(shortx4*)(Vt + idx) = pk;   // 4 consecutive t els
                }
    } else if constexpr (MODE == MODE_PROJ) {
        #pragma unroll
        for (int i = 0; i < 2; ++i)
            #pragma unroll
            for (int j = 0; j < 2; ++j)
                #pragma unroll
                for (int g = 0; g < 4; ++g)
                    #pragma unroll
                    for (int r = 0; r < 4; ++r) {
                        const int row = m0 + wm + 32 * i + g * 8 + 4 * lhalf + r;
                        const int col = n0 + wn + 32 * j + lrow;
                        C[sidx(row, col)] = __float2bfloat16(acc[i][j][4 * g + r]);
                    }
    } else if constexpr (MODE == MODE_EXP) {
        #pragma unroll
        for (int i = 0; i < 2; ++i) {
            float rsl[16];
            #pragma unroll
            for (int reg = 0; reg < 16; ++reg) rsl[reg] = 0.0f;
            #pragma unroll
            for (int j = 0; j < 2; ++j)
                #pragma unroll
                for (int g = 0; g < 4; ++g)
                    #pragma unroll
                    for (int r = 0; r < 4; ++r) {
                        const int row = m0 + wm + 32 * i + g * 8 + 4 * lhalf + r;
                        const int col = n0 + wn + 32 * j + lrow;
                        const float e = __expf(acc[i][j][4 * g + r] * alpha);
                        rsl[4 * g + r] += e;
                        C[sidx(row, col)] = __float2bfloat16(e);
                    }
            #pragma unroll
            for (int reg = 0; reg < 16; ++reg) {
                float v = rsl[reg];
                v += __shfl_xor(v, 1);
                v += __shfl_xor(v, 2);
                v += __shfl_xor(v, 4);
                v += __shfl_xor(v, 8);
                v += __shfl_xor(v, 16);
                if (lrow == 0) {
                    const long row = m0 + wm + 32 * i + (reg >> 2) * 8 + 4 * lhalf + (reg & 3);
                    atomicAdd(&rs[row], v);
                }
            }
        }
    } else {  // MODE_DIV: out row-major fp32
        #pragma unroll
        for (int i = 0; i < 2; ++i) {
            float inv[16];
            #pragma unroll
            for (int g = 0; g < 4; ++g)
                #pragma unroll
                for (int r = 0; r < 4; ++r) {
                    const long row = m0 + wm + 32 * i + g * 8 + 4 * lhalf + r;
                    inv[4 * g + r] = 1.0f / rs[row];
                }
            #pragma unroll
            for (int j = 0; j < 2; ++j)
                #pragma unroll
                for (int g = 0; g < 4; ++g)
                    #pragma unroll
                    for (int r = 0; r < 4; ++r) {
                        const long row = m0 + wm + 32 * i + g * 8 + 4 * lhalf + r;
                        const long col = n0 + wn + 32 * j + lrow;
                        C[row * N + col] = acc[i][j][4 * g + r] * inv[4 * g + r];
                    }
        }
    }
}

// ---- dispatch 2: Q,K projections (z=0 -> Q, z=1 -> K), grid (32,8,2) ----
__global__ __launch_bounds__(512, 4) void k_projqk(
    const __hip_bfloat16* __restrict__ xb, const __hip_bfloat16* __restrict__ Wb,
    __hip_bfloat16* __restrict__ Q)
{
    __shared__ __hip_bfloat16 lds[3 * 12288];   // 72KB
    const int z = blockIdx.z;
    gemm_core<MODE_PROJ, false>(
        xb, Wb + (long)z * 1048576, Q + (long)z * 8388608, nullptr, nullptr,
        1024, 1024, 1.0f, blockIdx.x * 256, blockIdx.y * 128, lds);
}

// ---- dispatch 3: fused exp (blocks 0..511) + projV (blocks 512..767) ----
__global__ __launch_bounds__(512, 4) void k_fused(
    const __hip_bfloat16* __restrict__ Q, const __hip_bfloat16* __restrict__ Kb,
    __hip_bfloat16* __restrict__ P, float* __restrict__ rowsum,
    const __hip_bfloat16* __restrict__ xb, const __hip_bfloat16* __restrict__ WbV,
    __hip_bfloat16* __restrict__ Vt)
{
    __shared__ __hip_bfloat16 lds[3 * 12288];   // 72KB
    const int bid = blockIdx.x;
    if (bid < 512) {
        // exp: P_z = exp(Q_z K_z^T / 32), rowsum_z += rows
        const int zb = bid >> 7;                // batch 0..3
        const int r  = bid & 127;
        const int m0 = (r & 7) * 256;           // T/256 = 8
        const int n0 = (r >> 3) * 128;          // T/128 = 16
        gemm_core<MODE_EXP, false>(
            Q  + (long)zb * 2097152, Kb + (long)zb * 2097152,
            P  + (long)zb * 4194304, rowsum + (long)zb * 2048, nullptr,
            2048, 1024, 0.03125f, m0, n0, lds);
    } else {
        // projV: Vt (striped, transposed) from xb @ WbV^T
        const int p  = bid - 512;               // 0..255
        const int m0 = (p & 31) * 256;          // M/256 = 32 (global rows)
        const int n0 = (p >> 5) * 128;          // D/128 = 8
        gemm_core<MODE_PROJ, true>(
            xb, WbV, nullptr, nullptr, Vt,
            1024, 1024, 1.0f, m0, n0, lds);
    }
}

// ---- dispatch 4: out = (P @ Vt^T) / rowsum[row], grid (8,8,4) ----
__global__ __launch_bounds__(512, 4) void k_div(
    const __hip_bfloat16* __restrict__ P, const __hip_bfloat16* __restrict__ Vt,
    float* __restrict__ out, float* __restrict__ rowsum)
{
    __shared__ __hip_bfloat16 lds[3 * 12288];   // 72KB
    const int z = blockIdx.z;
    gemm_core<MODE_DIV, false>(
        P + (long)z * 4194304, Vt + (long)z * 2097152,
        out + (long)z * 2097152, rowsum + (long)z * 2048, nullptr,
        1024, 2048, 1.0f, blockIdx.x * 256, blockIdx.y * 128, lds);
}

// prep: cast x / Wq|Wk|Wv fp32->bf16 into stripe layout via LDS transpose.
// Block = one 32-row group x K=1024: coalesced float4 reads -> striped LDS
// image (64KB) -> 64KB CONTIGUOUS global write. Blocks 0..255: xb;
// 256..351: Wb. Blocks 0..31 also zero rowsum.
__global__ __launch_bounds__(256) void prep(
    const float* __restrict__ x,
    const float* __restrict__ W0, const float* __restrict__ W1,
    const float* __restrict__ W2,
    __hip_bfloat16* __restrict__ xb, __hip_bfloat16* __restrict__ Wb,
    float* __restrict__ rowsum)
{
    __shared__ __hip_bfloat16 sb[32768];    // 64KB striped image

    const int b  = blockIdx.x;
    const int tt = threadIdx.x;             // 0..255

    if (b < 32) {
        float4 zz; zz.x = zz.y = zz.z = zz.w = 0.0f;
        ((float4*)rowsum)[b * 256 + tt] = zz;
    }

    const float* src;
    __hip_bfloat16* dst;
    if (b < 256) {
        src = x + (long)b * 32 * 1024;
        dst = xb + (long)b * 32768;
    } else {
        const int w  = (b - 256) >> 5;
        const int rg = (b - 256) & 31;
        src = ((w == 0) ? W0 : (w == 1) ? W1 : W2) + (long)rg * 32 * 1024;
        dst = Wb + (long)w * 1048576 + (long)rg * 32768;
    }

    #pragma unroll
    for (int it = 0; it < 32; ++it) {
        const int idx4 = it * 256 + tt;         // float4 index in row-major
        const float4 f = ((const float4*)src)[idx4];
        const int row = idx4 >> 8;              // 256 float4 per row
        const int k0  = (idx4 & 255) << 2;
        const int p   = ((row & 31) + 32 * ((k0 >> 3) & 1)) * 8 + (k0 & 7);
        shortx4 pk;
        __hip_bfloat16 h0 = __float2bfloat16(f.x); pk[0] = *(short*)&h0;
        __hip_bfloat16 h1 = __float2bfloat16(f.y); pk[1] = *(short*)&h1;
        __hip_bfloat16 h2 = __float2bfloat16(f.z); pk[2] = *(short*)&h2;
        __hip_bfloat16 h3 = __float2bfloat16(f.w); pk[3] = *(short*)&h3;
        *(shortx4*)(sb + (k0 >> 4) * 512 + p) = pk;
    }
    __syncthreads();

    #pragma unroll
    for (int ot = 0; ot < 16; ++ot) {
        const int off = ot * 2048 + tt * 8;
        *(shortx8*)(dst + off) = *(const shortx8*)(sb + off);
    }
}

extern "C" void kernel_launch(void* const* d_in, const int* in_sizes, int n_in,
                              void* d_out, int out_size, void* d_ws, size_t ws_size,
                              hipStream_t stream)
{
    constexpr int  Bb = 4, T = 2048, D = 1024;
    constexpr int  M  = Bb * T;                 // 8192
    constexpr long TT = (long)T * T;            // 4,194,304
    constexpr long MD = (long)M * D;            // 8,388,608

    const float* x  = (const float*)d_in[0];
    const float* Wq = (const float*)d_in[1];
    const float* Wk = (const float*)d_in[2];
    const float* Wv = (const float*)d_in[3];
    float* out = (float*)d_out;

    // workspace: Q|K|Vt (bf16 16MB each) | P (bf16 33.6MB) | xb (16MB)
    //            | Wb (6MB) | rowsum (32KB)   -> ~104 MB  (all striped)
    __hip_bfloat16* Q  = (__hip_bfloat16*)d_ws;
    __hip_bfloat16* Kb = Q + MD;
    __hip_bfloat16* Vt = Kb + MD;
    __hip_bfloat16* P  = Vt + MD;
    __hip_bfloat16* xb = P + (long)Bb * TT;
    __hip_bfloat16* Wb = xb + MD;
    float*     rowsum  = (float*)(Wb + 3L * D * D);

    // 1) cast/transpose inputs, zero rowsum
    prep<<<dim3(352), dim3(256), 0, stream>>>(x, Wq, Wk, Wv, xb, Wb, rowsum);

    // 2) Q,K projections (V deferred into dispatch 3)
    k_projqk<<<dim3(M / 256, D / 128, 2), dim3(512), 0, stream>>>(xb, Wb, Q);

    // 3) fused: P = exp(Q K^T / 32) + rowsum  ||  Vt = (xb @ Wv^T)^T
    k_fused<<<dim3(768), dim3(512), 0, stream>>>(
        Q, Kb, P, rowsum, xb, Wb + 2L * D * D, Vt);

    // 4) out = (P @ Vt^T) / rowsum[row]
    k_div<<<dim3(T / 256, D / 128, Bb), dim3(512), 0, stream>>>(
        P, Vt, out, rowsum);

    (void)in_sizes; (void)n_in; (void)out_size; (void)ws_size;
}